// Round 4
// baseline (449.744 us; speedup 1.0000x reference)
//
#include <hip/hip_runtime.h>

typedef unsigned long long u64;
typedef unsigned int u32;
typedef short short8 __attribute__((ext_vector_type(8)));
typedef float f32x4 __attribute__((ext_vector_type(4)));
typedef u32 u32x4v __attribute__((ext_vector_type(4)));

#define N_PTS   4096
#define B_SZ    4
#define L_TOK   16
#define FV      256
#define FL      768
#define FDIM    128
#define KNN     16
#define RH      64
#define NBLK    512

#define MFMA_BF16(a, b, c) __builtin_amdgcn_mfma_f32_16x16x32_bf16((a), (b), (c), 0, 0, 0)

__device__ __forceinline__ short f2bf(float f) {
    unsigned int x = __float_as_uint(f);
    unsigned int r = (x + 0x7fffu + ((x >> 16) & 1u)) >> 16;
    return (short)r;
}

// Split f32 into bf16 hi (truncation) and bf16 lo (residual), packed as
// (hi<<16)|lo. Returned by value: clang can't bind refs to vector elems.
__device__ __forceinline__ u32 splitf(float f) {
    u32 bits = __float_as_uint(f);
    u32 hi = bits >> 16;
    float lof = f - __uint_as_float(bits & 0xffff0000u);
    u32 lo = __float_as_uint(lof) >> 16;
    return (hi << 16) | lo;
}

// Device-scope grid barrier. Safe because the grid (512 blocks, 256 thr,
// <=256 VGPR via launch_bounds, 33.8KB LDS) is guaranteed 2 blocks/CU
// co-resident on 256 CUs. Counters are zeroed by hipMemsetAsync each launch.
__device__ __forceinline__ void grid_sync(unsigned* bar, int idx) {
    __syncthreads();
    if (threadIdx.x == 0) {
        __threadfence();   // release: publish this block's writes device-wide
        __hip_atomic_fetch_add(&bar[idx], 1u, __ATOMIC_ACQ_REL, __HIP_MEMORY_SCOPE_AGENT);
        while (__hip_atomic_load(&bar[idx], __ATOMIC_ACQUIRE, __HIP_MEMORY_SCOPE_AGENT) < NBLK)
            __builtin_amdgcn_s_sleep(8);
        __threadfence();   // acquire side
    }
    __syncthreads();
}

// =====================================================================
// MEGA KERNEL — whole pipeline in one launch, 4 phases, 3 grid barriers.
//  P1: kNN (2 q/wave, f64 bitonic sort-merge) + lang1 + W1/W2/Wr2 packs
//  P2: feat encoder (MFMA, features loaded direct + in-reg hi/lo split)
//      + lang2 (BN + GEMM)
//  P3: atten = feats·lang^T via split-bf16 MFMA (12 MFMA / 16 points)
//      + langp bf16 B-frag pack
//  P4: edge kernel (2 q/wave)
// =====================================================================
__global__ __launch_bounds__(256, 2) void mega_kernel(
    const float* __restrict__ xyz, const float* __restrict__ features,
    const float* __restrict__ lf, const float* __restrict__ mask,
    const float* __restrict__ W1, const float* __restrict__ b1,
    const float* __restrict__ ln_g, const float* __restrict__ ln_b,
    const float* __restrict__ W2, const float* __restrict__ b2,
    const float* __restrict__ Wl1, const float* __restrict__ bl1,
    const float* __restrict__ bn_g, const float* __restrict__ bn_b,
    const float* __restrict__ Wl2, const float* __restrict__ bl2,
    const float* __restrict__ Wr1, const float* __restrict__ br1,
    const float* __restrict__ Wr2, const float* __restrict__ br2,
    float* __restrict__ feats, float* __restrict__ atten,
    float* __restrict__ lang, float* __restrict__ hl, int* __restrict__ knn,
    short* __restrict__ w1p_hi, short* __restrict__ w1p_lo,
    short* __restrict__ w2p_hi, short* __restrict__ w2p_lo,
    short* __restrict__ w2pe, short* __restrict__ langp,
    unsigned* __restrict__ bar, float* __restrict__ out)
{
    __shared__ u32 smem_u[8448];   // 33792 B, reused per phase
    int b = blockIdx.x, t = threadIdx.x;
    int wid = t >> 6, lane = t & 63;
    int e = lane & 15, q = lane >> 4;

    // ================= PHASE 1 =================
    {
        // ---- kNN: 2 queries per wave ----
        for (int qq = 0; qq < 2; qq++) {
            int qi = (b * 4 + wid) * 2 + qq;
            int base = (qi >> 10) << 10;
            float qx = xyz[qi * 3 + 0];
            float qy = xyz[qi * 3 + 1];
            float qz = xyz[qi * 3 + 2];
            double key[16];
#pragma unroll
            for (int m = 0; m < 16; m++) {
                int jl = lane + (m << 6);
                int j = base + jl;
                float dx = qx - xyz[j * 3 + 0];
                float dy = qy - xyz[j * 3 + 1];
                float dz = qz - xyz[j * 3 + 2];
                float d2 = __fadd_rn(__fadd_rn(__fmul_rn(dx, dx), __fmul_rn(dy, dy)),
                                     __fmul_rn(dz, dz));
                key[m] = (double)__float_as_uint(d2) * 1024.0 + (double)jl;
            }
#pragma unroll
            for (int k = 2; k <= 16; k <<= 1) {
#pragma unroll
                for (int jj = k >> 1; jj > 0; jj >>= 1) {
#pragma unroll
                    for (int i = 0; i < 16; i++) {
                        int l = i ^ jj;
                        if (l > i) {
                            double lo = fmin(key[i], key[l]);
                            double hi = fmax(key[i], key[l]);
                            bool asc = ((i & k) == 0);
                            key[i] = asc ? lo : hi;
                            key[l] = asc ? hi : lo;
                        }
                    }
                }
            }
#pragma unroll
            for (int lvl = 1; lvl <= 32; lvl <<= 1) {
                double pk[16];
#pragma unroll
                for (int i = 0; i < 16; i++) pk[i] = __shfl_xor(key[15 - i], lvl, 64);
#pragma unroll
                for (int i = 0; i < 16; i++) key[i] = fmin(key[i], pk[i]);
#pragma unroll
                for (int jj = 8; jj > 0; jj >>= 1) {
#pragma unroll
                    for (int i = 0; i < 16; i++) {
                        int l = i ^ jj;
                        if (l > i) {
                            double lo = fmin(key[i], key[l]);
                            double hi = fmax(key[i], key[l]);
                            key[i] = lo;
                            key[l] = hi;
                        }
                    }
                }
            }
            if (lane == 0) {
                int idx[16];
#pragma unroll
                for (int i = 0; i < 16; i++)
                    idx[i] = base + (int)(((u64)key[i]) & 1023u);
#pragma unroll
                for (int w = 0; w < 4; w++) {
                    int4 v = {idx[4 * w], idx[4 * w + 1], idx[4 * w + 2], idx[4 * w + 3]};
                    *(int4*)&knn[qi * KNN + 4 * w] = v;
                }
            }
        }
        // ---- extra jobs, spread over blocks (stride 5) ----
        if (b % 5 == 0) {
            int ej = b / 5;
            if (ej < 64) {
                // lang1: hl[row ej] = lf[ej] @ Wl1 + bl1
                int r = ej;
                float* lrow = (float*)smem_u;        // [768]
                float* part = lrow + FL;             // [2][128]
                for (int k = t; k < FL; k += 256) lrow[k] = lf[r * FL + k];
                __syncthreads();
                int c = t & 127, kh = t >> 7;
                float acc = (kh == 0) ? bl1[c] : 0.f;
                int k0 = kh * 384;
                for (int k = k0; k < k0 + 384; k++) acc += lrow[k] * Wl1[k * FDIM + c];
                part[kh * FDIM + c] = acc;
                __syncthreads();
                if (kh == 0) hl[r * FDIM + c] = part[c] + part[FDIM + c];
            } else if (ej < 76) {
                // W1 (ks 0..7) / W2 (ks 0..3) hi/lo split pack, B-frag order
                int isW2 = (ej >= 72);
                int ks = isW2 ? (ej - 72) : (ej - 64);
                const float* W = isW2 ? W2 : W1;
                short* ph = isW2 ? w2p_hi : w1p_hi;
                short* pl = isW2 ? w2p_lo : w1p_lo;
#pragma unroll
                for (int p = 0; p < 2; p++) {
                    int ct = wid * 2 + p;
                    short8 hi, lo;
#pragma unroll
                    for (int j = 0; j < 8; j++) {
                        u32 pr = splitf(W[(ks * 32 + q * 8 + j) * FDIM + ct * 16 + e]);
                        hi[j] = (short)(pr >> 16);
                        lo[j] = (short)(pr & 0xffffu);
                    }
                    int o = ((ks * 8 + ct) * 64 + lane) * 8;
                    *(short8*)(ph + o) = hi;
                    *(short8*)(pl + o) = lo;
                }
            } else if (ej < 78) {
                // Wr2 bf16 pack (f2bf round), B-frag order
                int ks = ej - 76;
#pragma unroll
                for (int p = 0; p < 2; p++) {
                    int ct = wid * 2 + p;
                    short8 v;
#pragma unroll
                    for (int j = 0; j < 8; j++)
                        v[j] = f2bf(Wr2[(ks * 32 + q * 8 + j) * FDIM + ct * 16 + e]);
                    *(short8*)(w2pe + ((ks * 8 + ct) * 64 + lane) * 8) = v;
                }
            }
        }
    }
    grid_sync(bar, 0);

    // ================= PHASE 2 =================
    if (b < 64) {
        // ---- feat encoder: MFMA, 16 rows/wave ----
        int rt = b * 4 + wid;
        f32x4 acc[8];
#pragma unroll
        for (int ct = 0; ct < 8; ct++) {
            float v = b1[ct * 16 + e];
            acc[ct] = (f32x4){v, v, v, v};
        }
        for (int ks = 0; ks < 8; ks++) {
            const float* src = features + (rt * 16 + e) * FV + ks * 32 + q * 8;
            float4 f0 = *(const float4*)src;
            float4 f1 = *(const float4*)(src + 4);
            float av[8] = {f0.x, f0.y, f0.z, f0.w, f1.x, f1.y, f1.z, f1.w};
            short8 ah, al;
#pragma unroll
            for (int j = 0; j < 8; j++) {
                u32 pr = splitf(av[j]);
                ah[j] = (short)(pr >> 16);
                al[j] = (short)(pr & 0xffffu);
            }
#pragma unroll
            for (int ct = 0; ct < 8; ct++) {
                int bo = ((ks * 8 + ct) * 64 + lane) * 8;
                short8 bh = *(const short8*)(w1p_hi + bo);
                short8 bl = *(const short8*)(w1p_lo + bo);
                acc[ct] = MFMA_BF16(ah, bh, acc[ct]);
                acc[ct] = MFMA_BF16(al, bh, acc[ct]);
                acc[ct] = MFMA_BF16(ah, bl, acc[ct]);
            }
        }
        // LayerNorm (rows on (q,reg); reduce over e via 16-lane shfl)
        float s[4], sq[4];
#pragma unroll
        for (int r = 0; r < 4; r++) { s[r] = 0.f; sq[r] = 0.f; }
#pragma unroll
        for (int ct = 0; ct < 8; ct++)
#pragma unroll
            for (int r = 0; r < 4; r++) {
                float v = acc[ct][r];
                s[r] += v; sq[r] += v * v;
            }
#pragma unroll
        for (int off = 1; off < 16; off <<= 1)
#pragma unroll
            for (int r = 0; r < 4; r++) {
                s[r] += __shfl_xor(s[r], off, 16);
                sq[r] += __shfl_xor(sq[r], off, 16);
            }
        float mu[4], rs[4];
#pragma unroll
        for (int r = 0; r < 4; r++) {
            mu[r] = s[r] * (1.f / 128.f);
            float var = sq[r] * (1.f / 128.f) - mu[r] * mu[r];
            rs[r] = rsqrtf(var + 1e-5f);
        }
        // normalize + ReLU + split-pack -> LDS transpose (stride 132)
        u32* hrow = smem_u + wid * (16 * 132);
#pragma unroll
        for (int ct = 0; ct < 8; ct++) {
            float g = ln_g[ct * 16 + e], bb = ln_b[ct * 16 + e];
#pragma unroll
            for (int r = 0; r < 4; r++) {
                float n = fmaxf((acc[ct][r] - mu[r]) * rs[r] * g + bb, 0.f);
                hrow[(q * 4 + r) * 132 + ct * 16 + e] = splitf(n);
            }
        }
        // GEMM2
        f32x4 acc2[8];
#pragma unroll
        for (int ct = 0; ct < 8; ct++) {
            float v = b2[ct * 16 + e];
            acc2[ct] = (f32x4){v, v, v, v};
        }
#pragma unroll
        for (int ks = 0; ks < 4; ks++) {
            u32 hv[8];
            *(u32x4v*)&hv[0] = *(const u32x4v*)&hrow[e * 132 + ks * 32 + q * 8];
            *(u32x4v*)&hv[4] = *(const u32x4v*)&hrow[e * 132 + ks * 32 + q * 8 + 4];
            short8 ah, al;
#pragma unroll
            for (int j = 0; j < 8; j++) {
                ah[j] = (short)(hv[j] >> 16);
                al[j] = (short)(hv[j] & 0xffffu);
            }
#pragma unroll
            for (int ct = 0; ct < 8; ct++) {
                int bo = ((ks * 8 + ct) * 64 + lane) * 8;
                short8 bh = *(const short8*)(w2p_hi + bo);
                short8 bl = *(const short8*)(w2p_lo + bo);
                acc2[ct] = MFMA_BF16(ah, bh, acc2[ct]);
                acc2[ct] = MFMA_BF16(al, bh, acc2[ct]);
                acc2[ct] = MFMA_BF16(ah, bl, acc2[ct]);
            }
        }
#pragma unroll
        for (int ct = 0; ct < 8; ct++)
#pragma unroll
            for (int r = 0; r < 4; r++)
                feats[(rt * 16 + q * 4 + r) * FDIM + ct * 16 + e] = acc2[ct][r];
    } else if (b < 80) {
        // ---- lang2: BN (batch stats) + ReLU + GEMM2, 4 rows/block ----
        float* rl4 = (float*)smem_u;          // [4][128]
        int tt = t & 127;
        int act = (t < 128);
        int r0 = (b - 64) * 4;
        if (act) {
            float s = 0.f, s2 = 0.f;
            for (int r = 0; r < 64; r++) {
                float v = hl[r * FDIM + tt];
                s += v; s2 += v * v;
            }
            float mu = s * (1.f / 64.f);
            float var = s2 * (1.f / 64.f) - mu * mu;
            float rs = rsqrtf(var + 1e-5f);
            float g = bn_g[tt], bb = bn_b[tt];
#pragma unroll
            for (int p = 0; p < 4; p++)
                rl4[p * FDIM + tt] = fmaxf((hl[(r0 + p) * FDIM + tt] - mu) * rs * g + bb, 0.f);
        }
        __syncthreads();
        if (act) {
            float bv = bl2[tt];
            float a0 = bv, a1 = bv, a2 = bv, a3 = bv;
            for (int k = 0; k < FDIM; k++) {
                float w = Wl2[k * FDIM + tt];
                a0 += rl4[0 * FDIM + k] * w;
                a1 += rl4[1 * FDIM + k] * w;
                a2 += rl4[2 * FDIM + k] * w;
                a3 += rl4[3 * FDIM + k] * w;
            }
            lang[(r0 + 0) * FDIM + tt] = a0;
            lang[(r0 + 1) * FDIM + tt] = a1;
            lang[(r0 + 2) * FDIM + tt] = a2;
            lang[(r0 + 3) * FDIM + tt] = a3;
        }
    }
    grid_sync(bar, 1);

    // ================= PHASE 3 =================
    if (b < 64) {
        // ---- atten via split-bf16 MFMA: 16 points per wave ----
        // A[m=pt][k=feat], B[k=feat][n=l]=lang[l][k]; C row=pt(q*4+r), col=l(e)
        int pt0 = (b * 4 + wid) * 16;
        int bi = pt0 >> 10;
        const float* arow = feats + (pt0 + e) * FDIM;
        const float* brow = lang + (bi * L_TOK + e) * FDIM;
        f32x4 acc = {0.f, 0.f, 0.f, 0.f};
#pragma unroll
        for (int ks = 0; ks < 4; ks++) {
            int off = ks * 32 + q * 8;
            float4 a0 = *(const float4*)(arow + off);
            float4 a1 = *(const float4*)(arow + off + 4);
            float4 c0 = *(const float4*)(brow + off);
            float4 c1 = *(const float4*)(brow + off + 4);
            float av[8] = {a0.x, a0.y, a0.z, a0.w, a1.x, a1.y, a1.z, a1.w};
            float bv[8] = {c0.x, c0.y, c0.z, c0.w, c1.x, c1.y, c1.z, c1.w};
            short8 ah, al, bh, bl;
#pragma unroll
            for (int j = 0; j < 8; j++) {
                u32 pa = splitf(av[j]);
                u32 pb = splitf(bv[j]);
                ah[j] = (short)(pa >> 16);
                al[j] = (short)(pa & 0xffffu);
                bh[j] = (short)(pb >> 16);
                bl[j] = (short)(pb & 0xffffu);
            }
            acc = MFMA_BF16(ah, bh, acc);
            acc = MFMA_BF16(al, bh, acc);
            acc = MFMA_BF16(ah, bl, acc);
        }
#pragma unroll
        for (int r = 0; r < 4; r++)
            atten[(pt0 + q * 4 + r) * L_TOK + e] = acc[r];
    } else if (b < 68) {
        // ---- langp: lang -> bf16 B-frag pack for edge ctx MFMA ----
        int bi = b - 64;
#pragma unroll
        for (int p = 0; p < 2; p++) {
            int tile = wid * 2 + p;
            short8 v;
            if (q < 2) {
#pragma unroll
                for (int j = 0; j < 8; j++)
                    v[j] = f2bf(lang[bi * L_TOK * FDIM + (q * 8 + j) * FDIM + tile * 16 + e]);
            } else {
#pragma unroll
                for (int j = 0; j < 8; j++) v[j] = 0;
            }
            *(short8*)(langp + ((bi * 8 + tile) * 64 + lane) * 8) = v;
        }
    }
    grid_sync(bar, 2);

    // ================= PHASE 4: edge, 2 queries/wave =================
    for (int qq = 0; qq < 2; qq++) {
        int i = (b * 4 + wid) * 2 + qq;
        int bi = i >> 10;
        int quad = q;
        int e16 = e;

        int idxe = knn[i * KNN + e16];

        float sat[8];
        if (quad < 2) {
            const float4* ap = (const float4*)(atten + idxe * L_TOK + quad * 8);
            float4 a0 = ap[0], a1 = ap[1];
            sat[0] = a0.x; sat[1] = a0.y; sat[2] = a0.z; sat[3] = a0.w;
            sat[4] = a1.x; sat[5] = a1.y; sat[6] = a1.z; sat[7] = a1.w;
        } else {
#pragma unroll
            for (int j = 0; j < 8; j++) sat[j] = 0.f;
        }

        float mx[8];
#pragma unroll
        for (int j = 0; j < 8; j++) mx[j] = sat[j];
#pragma unroll
        for (int off = 1; off < 16; off <<= 1) {
#pragma unroll
            for (int j = 0; j < 8; j++) mx[j] = fmaxf(mx[j], __shfl_xor(mx[j], off, 16));
        }
        float ex[8], sm[8];
#pragma unroll
        for (int j = 0; j < 8; j++) { ex[j] = __expf(sat[j] - mx[j]); sm[j] = ex[j]; }
#pragma unroll
        for (int off = 1; off < 16; off <<= 1) {
#pragma unroll
            for (int j = 0; j < 8; j++) sm[j] += __shfl_xor(sm[j], off, 16);
        }
        float st[8];
        if (quad < 2) {
            const float4* mp = (const float4*)(mask + i * L_TOK + quad * 8);
            float4 m0 = mp[0], m1 = mp[1];
            float mv[8] = {m0.x, m0.y, m0.z, m0.w, m1.x, m1.y, m1.z, m1.w};
#pragma unroll
            for (int j = 0; j < 8; j++) st[j] = ex[j] * (mv[j] / sm[j]);
        } else {
#pragma unroll
            for (int j = 0; j < 8; j++) st[j] = 0.f;
        }
        float s = st[0] + st[1] + st[2] + st[3] + st[4] + st[5] + st[6] + st[7];
        s += __shfl_xor(s, 16, 64);
        s += __shfl_xor(s, 32, 64);
        float inv2 = 1.f / (s + 1e-7f);
        short8 sattA;
#pragma unroll
        for (int j = 0; j < 8; j++) sattA[j] = f2bf(st[j] * inv2);

        float xi0 = xyz[i * 3 + 0], xi1 = xyz[i * 3 + 1], xi2 = xyz[i * 3 + 2];
        float xj0 = xyz[idxe * 3 + 0], xj1 = xyz[idxe * 3 + 1], xj2 = xyz[idxe * 3 + 2];
        float d0 = xi0 - xj0, d1 = xi1 - xj1, d2v = xi2 - xj2;
        float nr = sqrtf(d0 * d0 + d1 * d1 + d2v * d2v + 1e-12f);
        float ein[10] = {xi0, xi1, xi2, xj0, xj1, xj2, d0, d1, d2v, nr};
        short8 hidA[2];
#pragma unroll
        for (int sstep = 0; sstep < 2; sstep++) {
            int k0 = sstep * 32 + quad * 8;
            float h[8];
            const float4* bp = (const float4*)(br1 + k0);
            float4 b0 = bp[0], b1v = bp[1];
            h[0] = b0.x; h[1] = b0.y; h[2] = b0.z; h[3] = b0.w;
            h[4] = b1v.x; h[5] = b1v.y; h[6] = b1v.z; h[7] = b1v.w;
#pragma unroll
            for (int m = 0; m < 10; m++) {
                const float4* wp = (const float4*)(Wr1 + m * RH + k0);
                float4 w0 = wp[0], w1 = wp[1];
                float em = ein[m];
                h[0] += em * w0.x; h[1] += em * w0.y; h[2] += em * w0.z; h[3] += em * w0.w;
                h[4] += em * w1.x; h[5] += em * w1.y; h[6] += em * w1.z; h[7] += em * w1.w;
            }
#pragma unroll
            for (int j = 0; j < 8; j++) hidA[sstep][j] = f2bf(fmaxf(h[j], 0.f));
        }

        int idxr[4];
#pragma unroll
        for (int r = 0; r < 4; r++) idxr[r] = knn[i * KNN + quad * 4 + r];

#pragma unroll 2
        for (int tile = 0; tile < 8; tile++) {
            int cc = tile * 16 + e16;
            f32x4 accew = {0.f, 0.f, 0.f, 0.f};
#pragma unroll
            for (int sstep = 0; sstep < 2; sstep++) {
                short8 w2B = *(const short8*)(w2pe + ((sstep * 8 + tile) * 64 + lane) * 8);
                accew = MFMA_BF16(hidA[sstep], w2B, accew);
            }
            short8 lsB = *(const short8*)(langp + ((bi * 8 + tile) * 64 + lane) * 8);
            f32x4 accctx = {0.f, 0.f, 0.f, 0.f};
            accctx = MFMA_BF16(sattA, lsB, accctx);

            float br2c = br2[cc];
            float msum = 0.f;
#pragma unroll
            for (int r = 0; r < 4; r++) {
                float fj = feats[idxr[r] * FDIM + cc];
                msum += fj * accctx[r] * (accew[r] + br2c);
            }
            msum += __shfl_xor(msum, 16, 64);
            msum += __shfl_xor(msum, 32, 64);
            if (lane < 16)
                out[i * FDIM + cc] = feats[i * FDIM + cc] + msum;
        }
    }
}

extern "C" void kernel_launch(void* const* d_in, const int* in_sizes, int n_in,
                              void* d_out, int out_size, void* d_ws, size_t ws_size,
                              hipStream_t stream) {
    const float* xyz   = (const float*)d_in[0];
    // d_in[1] = batch_index (int32) — layout-implied (i>>10), unused
    const float* features = (const float*)d_in[2];
    const float* lang_f   = (const float*)d_in[3];
    const float* mask     = (const float*)d_in[4];
    const float* W1   = (const float*)d_in[5];
    const float* b1   = (const float*)d_in[6];
    const float* ln_g = (const float*)d_in[7];
    const float* ln_b = (const float*)d_in[8];
    const float* W2   = (const float*)d_in[9];
    const float* b2   = (const float*)d_in[10];
    const float* Wl1  = (const float*)d_in[11];
    const float* bl1  = (const float*)d_in[12];
    const float* bn_g = (const float*)d_in[13];
    const float* bn_b = (const float*)d_in[14];
    const float* Wl2  = (const float*)d_in[15];
    const float* bl2  = (const float*)d_in[16];
    const float* Wr1  = (const float*)d_in[17];
    const float* br1  = (const float*)d_in[18];
    const float* Wr2  = (const float*)d_in[19];
    const float* br2  = (const float*)d_in[20];

    float* ws_feats = (float*)d_ws;                       // N*F
    float* ws_atten = ws_feats + N_PTS * FDIM;            // N*L
    float* ws_lang  = ws_atten + N_PTS * L_TOK;           // B*L*F
    float* ws_hl    = ws_lang + B_SZ * L_TOK * FDIM;      // 64*F
    int*   ws_knn   = (int*)(ws_hl + 64 * FDIM);          // N*K
    short* w1p_hi   = (short*)(ws_knn + N_PTS * KNN);     // FV*F bf16
    short* w1p_lo   = w1p_hi + FV * FDIM;
    short* w2p_hi   = w1p_lo + FV * FDIM;                 // F*F
    short* w2p_lo   = w2p_hi + FDIM * FDIM;
    short* w2pe     = w2p_lo + FDIM * FDIM;               // RH*F bf16 (f2bf)
    short* langp    = w2pe + RH * FDIM;                   // B*8*64*8 bf16
    unsigned* bar   = (unsigned*)(langp + B_SZ * 8 * 64 * 8);  // 3 barrier ctrs

    (void)hipMemsetAsync((void*)bar, 0, 3 * sizeof(unsigned), stream);
    mega_kernel<<<NBLK, 256, 0, stream>>>(
        xyz, features, lang_f, mask,
        W1, b1, ln_g, ln_b, W2, b2,
        Wl1, bl1, bn_g, bn_b, Wl2, bl2,
        Wr1, br1, Wr2, br2,
        ws_feats, ws_atten, ws_lang, ws_hl, ws_knn,
        w1p_hi, w1p_lo, w2p_hi, w2p_lo, w2pe, langp,
        bar, (float*)d_out);
}

// Round 5
// 163.323 us; speedup vs baseline: 2.7537x; 2.7537x over previous
//
#include <hip/hip_runtime.h>

typedef unsigned long long u64;
typedef unsigned int u32;
typedef short short8 __attribute__((ext_vector_type(8)));
typedef float f32x4 __attribute__((ext_vector_type(4)));
typedef u32 u32x4v __attribute__((ext_vector_type(4)));

#define N_PTS   4096
#define B_SZ    4
#define L_TOK   16
#define FV      256
#define FL      768
#define FDIM    128
#define KNN     16
#define RH      64

#define MFMA_BF16(a, b, c) __builtin_amdgcn_mfma_f32_16x16x32_bf16((a), (b), (c), 0, 0, 0)

__device__ __forceinline__ short f2bf(float f) {
    unsigned int x = __float_as_uint(f);
    unsigned int r = (x + 0x7fffu + ((x >> 16) & 1u)) >> 16;
    return (short)r;
}

// Split f32 into bf16 hi (truncation) and bf16 lo (residual), packed (hi<<16)|lo.
__device__ __forceinline__ u32 splitf(float f) {
    u32 bits = __float_as_uint(f);
    u32 hi = bits >> 16;
    float lof = f - __uint_as_float(bits & 0xffff0000u);
    u32 lo = __float_as_uint(lof) >> 16;
    return (hi << 16) | lo;
}

// =====================================================================
// K1: fused independent work, 256-thread blocks:
//   [0,1024)     kNN, 1 query/wave; xyz segment staged in LDS (12 KB,
//                shared by the block's 4 queries). f64 bitonic sort-merge;
//                the FINAL merge's cleanup is skipped (set-only output —
//                all downstream ops are segment sums, permutation-inv).
//   [1024,1088)  lang1: hl = lf @ Wl1 + bl1 (1 row/block)
//   [1088,1100)  W1/W2 hi/lo split packs (B-frag order)
//   [1100,1102)  Wr2 bf16 pack (B-frag order)
// NOTE round-4 lesson: software grid barriers cost ~100us each on MI355X
// (agent-scope acquire polling = cache-maintenance storm). Multi-kernel
// pipeline with stream ordering is strictly better here.
// =====================================================================
__global__ __launch_bounds__(256) void k1_kernel(const float* __restrict__ xyz,
                                                 const float* __restrict__ lf,
                                                 const float* __restrict__ Wl1,
                                                 const float* __restrict__ bl1,
                                                 const float* __restrict__ W1,
                                                 const float* __restrict__ W2,
                                                 const float* __restrict__ Wr2,
                                                 int* __restrict__ knn,
                                                 float* __restrict__ hl,
                                                 short* __restrict__ w1p_hi,
                                                 short* __restrict__ w1p_lo,
                                                 short* __restrict__ w2p_hi,
                                                 short* __restrict__ w2p_lo,
                                                 short* __restrict__ w2pe) {
    __shared__ float smem[3072];
    int b = blockIdx.x, t = threadIdx.x;
    int wid = t >> 6, lane = t & 63;
    int e = lane & 15, q = lane >> 4;

    if (b < 1024) {
        // ---------------- kNN: one query per wave, LDS-staged xyz -------
        int base = ((b * 4) >> 10) << 10;     // 4 queries share one segment
        for (int idx = t; idx < 3072; idx += 256) smem[idx] = xyz[base * 3 + idx];
        __syncthreads();
        int qi = b * 4 + wid;
        int ql = qi - base;
        float qx = smem[ql * 3 + 0];
        float qy = smem[ql * 3 + 1];
        float qz = smem[ql * 3 + 2];
        double key[16];
#pragma unroll
        for (int m = 0; m < 16; m++) {
            int jl = lane + (m << 6);
            float dx = qx - smem[jl * 3 + 0];
            float dy = qy - smem[jl * 3 + 1];
            float dz = qz - smem[jl * 3 + 2];
            // match reference rounding: no fma contraction, (x+y) then +z
            float d2 = __fadd_rn(__fadd_rn(__fmul_rn(dx, dx), __fmul_rn(dy, dy)),
                                 __fmul_rn(dz, dz));
            key[m] = (double)__float_as_uint(d2) * 1024.0 + (double)jl;
        }
        // per-lane bitonic sort, ascending (80 CEs, f64 min/max = 2 instr)
#pragma unroll
        for (int k = 2; k <= 16; k <<= 1) {
#pragma unroll
            for (int jj = k >> 1; jj > 0; jj >>= 1) {
#pragma unroll
                for (int i = 0; i < 16; i++) {
                    int l = i ^ jj;
                    if (l > i) {
                        double lo = fmin(key[i], key[l]);
                        double hi = fmax(key[i], key[l]);
                        bool asc = ((i & k) == 0);
                        key[i] = asc ? lo : hi;
                        key[l] = asc ? hi : lo;
                    }
                }
            }
        }
        // 6 merge levels over lanes: keep lowest-16 of (mine ∪ partner)
#pragma unroll
        for (int lvl = 1; lvl <= 32; lvl <<= 1) {
            double pk[16];
#pragma unroll
            for (int i = 0; i < 16; i++) pk[i] = __shfl_xor(key[15 - i], lvl, 64);
#pragma unroll
            for (int i = 0; i < 16; i++) key[i] = fmin(key[i], pk[i]);
            if (lvl != 32) {
                // bitonic cleanup (needed only so the NEXT level sees sorted lists)
#pragma unroll
                for (int jj = 8; jj > 0; jj >>= 1) {
#pragma unroll
                    for (int i = 0; i < 16; i++) {
                        int l = i ^ jj;
                        if (l > i) {
                            double lo = fmin(key[i], key[l]);
                            double hi = fmax(key[i], key[l]);
                            key[i] = lo;
                            key[l] = hi;
                        }
                    }
                }
            }
        }
        if (lane == 0) {
            int idx[16];
#pragma unroll
            for (int i = 0; i < 16; i++)
                idx[i] = base + (int)(((u64)key[i]) & 1023u);
#pragma unroll
            for (int w = 0; w < 4; w++) {
                int4 v = {idx[4 * w], idx[4 * w + 1], idx[4 * w + 2], idx[4 * w + 3]};
                *(int4*)&knn[qi * KNN + 4 * w] = v;
            }
        }
    } else if (b < 1088) {
        // ---------------- lang1: hl = lang_row @ Wl1 + bl1 ------
        int r = b - 1024;
        float* lrow = smem;          // [768]
        float* part = smem + 768;    // [2][128]
        for (int k = t; k < FL; k += 256) lrow[k] = lf[r * FL + k];
        __syncthreads();
        int c = t & 127, kh = t >> 7;
        float acc = (kh == 0) ? bl1[c] : 0.f;
        int k0 = kh * 384;
        for (int k = k0; k < k0 + 384; k++) acc += lrow[k] * Wl1[k * FDIM + c];
        part[kh * FDIM + c] = acc;
        __syncthreads();
        if (kh == 0) hl[r * FDIM + c] = part[c] + part[FDIM + c];
    } else if (b < 1100) {
        // ------------- W1/W2 hi/lo split pack (B-frag order) -----------
        int isW2 = (b >= 1096);
        int ks = isW2 ? (b - 1096) : (b - 1088);
        const float* W = isW2 ? W2 : W1;
        short* ph = isW2 ? w2p_hi : w1p_hi;
        short* pl = isW2 ? w2p_lo : w1p_lo;
#pragma unroll
        for (int p = 0; p < 2; p++) {
            int ct = wid * 2 + p;
            short8 hi, lo;
#pragma unroll
            for (int j = 0; j < 8; j++) {
                u32 pr = splitf(W[(ks * 32 + q * 8 + j) * FDIM + ct * 16 + e]);
                hi[j] = (short)(pr >> 16);
                lo[j] = (short)(pr & 0xffffu);
            }
            int o = ((ks * 8 + ct) * 64 + lane) * 8;
            *(short8*)(ph + o) = hi;
            *(short8*)(pl + o) = lo;
        }
    } else {
        // ------------- Wr2 bf16 pack (f2bf round), B-frag order --------
        int ks = b - 1100;           // 0..1 (K = 64)
#pragma unroll
        for (int p = 0; p < 2; p++) {
            int ct = wid * 2 + p;
            short8 v;
#pragma unroll
            for (int j = 0; j < 8; j++)
                v[j] = f2bf(Wr2[(ks * 32 + q * 8 + j) * FDIM + ct * 16 + e]);
            *(short8*)(w2pe + ((ks * 8 + ct) * 64 + lane) * 8) = v;
        }
    }
}

// =====================================================================
// K2: feat encoder via MFMA, features loaded DIRECT from global with
// in-register hi/lo split (blocks [0,64)) + lang stage 2 ([64,80)).
// =====================================================================
__global__ __launch_bounds__(256) void k2_kernel(const float* __restrict__ features,
                                                 const short* __restrict__ w1p_hi,
                                                 const short* __restrict__ w1p_lo,
                                                 const short* __restrict__ w2p_hi,
                                                 const short* __restrict__ w2p_lo,
                                                 const float* __restrict__ b1,
                                                 const float* __restrict__ ln_g,
                                                 const float* __restrict__ ln_b,
                                                 const float* __restrict__ b2,
                                                 const float* __restrict__ hl,
                                                 const float* __restrict__ bn_g,
                                                 const float* __restrict__ bn_b,
                                                 const float* __restrict__ Wl2,
                                                 const float* __restrict__ bl2,
                                                 float* __restrict__ feats,
                                                 float* __restrict__ lang) {
    __shared__ u32 smem_u[8448];
    int b = blockIdx.x, t = threadIdx.x;
    int wid = t >> 6, lane = t & 63;
    int e = lane & 15, q = lane >> 4;
    if (b < 64) {
        int rt = b * 4 + wid;               // rows rt*16 .. rt*16+16
        // ---- GEMM1: h = features @ W1 + b1 (split-bf16, 3 MFMA) ----
        f32x4 acc[8];
#pragma unroll
        for (int ct = 0; ct < 8; ct++) {
            float v = b1[ct * 16 + e];
            acc[ct] = (f32x4){v, v, v, v};
        }
        for (int ks = 0; ks < 8; ks++) {
            const float* src = features + (rt * 16 + e) * FV + ks * 32 + q * 8;
            float4 f0 = *(const float4*)src;
            float4 f1 = *(const float4*)(src + 4);
            float av[8] = {f0.x, f0.y, f0.z, f0.w, f1.x, f1.y, f1.z, f1.w};
            short8 ah, al;
#pragma unroll
            for (int j = 0; j < 8; j++) {
                u32 pr = splitf(av[j]);
                ah[j] = (short)(pr >> 16);
                al[j] = (short)(pr & 0xffffu);
            }
#pragma unroll
            for (int ct = 0; ct < 8; ct++) {
                int bo = ((ks * 8 + ct) * 64 + lane) * 8;
                short8 bh = *(const short8*)(w1p_hi + bo);
                short8 bl = *(const short8*)(w1p_lo + bo);
                acc[ct] = MFMA_BF16(ah, bh, acc[ct]);
                acc[ct] = MFMA_BF16(al, bh, acc[ct]);
                acc[ct] = MFMA_BF16(ah, bl, acc[ct]);
            }
        }
        // ---- LayerNorm (rows on (q,reg); 16-lane shfl reduce over e) ----
        float s[4], sq[4];
#pragma unroll
        for (int r = 0; r < 4; r++) { s[r] = 0.f; sq[r] = 0.f; }
#pragma unroll
        for (int ct = 0; ct < 8; ct++)
#pragma unroll
            for (int r = 0; r < 4; r++) {
                float v = acc[ct][r];
                s[r] += v; sq[r] += v * v;
            }
#pragma unroll
        for (int off = 1; off < 16; off <<= 1)
#pragma unroll
            for (int r = 0; r < 4; r++) {
                s[r] += __shfl_xor(s[r], off, 16);
                sq[r] += __shfl_xor(sq[r], off, 16);
            }
        float mu[4], rs[4];
#pragma unroll
        for (int r = 0; r < 4; r++) {
            mu[r] = s[r] * (1.f / 128.f);
            float var = sq[r] * (1.f / 128.f) - mu[r] * mu[r];
            rs[r] = rsqrtf(var + 1e-5f);
        }
        // ---- normalize + ReLU + split-pack -> LDS transpose (stride 132) ----
        u32* hrow = smem_u + wid * (16 * 132);
#pragma unroll
        for (int ct = 0; ct < 8; ct++) {
            float g = ln_g[ct * 16 + e], bb = ln_b[ct * 16 + e];
#pragma unroll
            for (int r = 0; r < 4; r++) {
                float n = fmaxf((acc[ct][r] - mu[r]) * rs[r] * g + bb, 0.f);
                hrow[(q * 4 + r) * 132 + ct * 16 + e] = splitf(n);
            }
        }
        // ---- GEMM2 ----
        f32x4 acc2[8];
#pragma unroll
        for (int ct = 0; ct < 8; ct++) {
            float v = b2[ct * 16 + e];
            acc2[ct] = (f32x4){v, v, v, v};
        }
#pragma unroll
        for (int ks = 0; ks < 4; ks++) {
            u32 hv[8];
            *(u32x4v*)&hv[0] = *(const u32x4v*)&hrow[e * 132 + ks * 32 + q * 8];
            *(u32x4v*)&hv[4] = *(const u32x4v*)&hrow[e * 132 + ks * 32 + q * 8 + 4];
            short8 ah, al;
#pragma unroll
            for (int j = 0; j < 8; j++) {
                ah[j] = (short)(hv[j] >> 16);
                al[j] = (short)(hv[j] & 0xffffu);
            }
#pragma unroll
            for (int ct = 0; ct < 8; ct++) {
                int bo = ((ks * 8 + ct) * 64 + lane) * 8;
                short8 bh = *(const short8*)(w2p_hi + bo);
                short8 bl = *(const short8*)(w2p_lo + bo);
                acc2[ct] = MFMA_BF16(ah, bh, acc2[ct]);
                acc2[ct] = MFMA_BF16(al, bh, acc2[ct]);
                acc2[ct] = MFMA_BF16(ah, bl, acc2[ct]);
            }
        }
#pragma unroll
        for (int ct = 0; ct < 8; ct++)
#pragma unroll
            for (int r = 0; r < 4; r++)
                feats[(rt * 16 + q * 4 + r) * FDIM + ct * 16 + e] = acc2[ct][r];
    } else {
        // ---- lang2: BN (batch stats) + ReLU + GEMM2, 4 rows/block ----
        float* rl4 = (float*)smem_u;          // [4][128]
        int tt = t & 127;
        int act = (t < 128);
        int r0 = (b - 64) * 4;
        if (act) {
            float s = 0.f, s2 = 0.f;
            for (int r = 0; r < 64; r++) {
                float v = hl[r * FDIM + tt];
                s += v; s2 += v * v;
            }
            float mu = s * (1.f / 64.f);
            float var = s2 * (1.f / 64.f) - mu * mu;
            float rs = rsqrtf(var + 1e-5f);
            float g = bn_g[tt], bb = bn_b[tt];
#pragma unroll
            for (int p = 0; p < 4; p++)
                rl4[p * FDIM + tt] = fmaxf((hl[(r0 + p) * FDIM + tt] - mu) * rs * g + bb, 0.f);
        }
        __syncthreads();
        if (act) {
            float bv = bl2[tt];
            float a0 = bv, a1 = bv, a2 = bv, a3 = bv;
            for (int k = 0; k < FDIM; k++) {
                float w = Wl2[k * FDIM + tt];
                a0 += rl4[0 * FDIM + k] * w;
                a1 += rl4[1 * FDIM + k] * w;
                a2 += rl4[2 * FDIM + k] * w;
                a3 += rl4[3 * FDIM + k] * w;
            }
            lang[(r0 + 0) * FDIM + tt] = a0;
            lang[(r0 + 1) * FDIM + tt] = a1;
            lang[(r0 + 2) * FDIM + tt] = a2;
            lang[(r0 + 3) * FDIM + tt] = a3;
        }
    }
}

// =====================================================================
// K3: atten via split-bf16 MFMA, 16 points/wave (blocks [0,64))
//     + langp bf16 B-frag pack ([64,68)).
// =====================================================================
__global__ __launch_bounds__(256) void atten_kernel(const float* __restrict__ feats,
                                                    const float* __restrict__ lang,
                                                    float* __restrict__ atten,
                                                    short* __restrict__ langp) {
    int b = blockIdx.x, t = threadIdx.x;
    int wid = t >> 6, lane = t & 63;
    int e = lane & 15, q = lane >> 4;
    if (b < 64) {
        // A[m=pt][k=feat], B[k=feat][n=l]=lang[l][k]; C row=pt(q*4+r), col=l(e)
        int pt0 = (b * 4 + wid) * 16;
        int bi = pt0 >> 10;
        const float* arow = feats + (pt0 + e) * FDIM;
        const float* brow = lang + (bi * L_TOK + e) * FDIM;
        f32x4 acc = {0.f, 0.f, 0.f, 0.f};
#pragma unroll
        for (int ks = 0; ks < 4; ks++) {
            int off = ks * 32 + q * 8;
            float4 a0 = *(const float4*)(arow + off);
            float4 a1 = *(const float4*)(arow + off + 4);
            float4 c0 = *(const float4*)(brow + off);
            float4 c1 = *(const float4*)(brow + off + 4);
            float av[8] = {a0.x, a0.y, a0.z, a0.w, a1.x, a1.y, a1.z, a1.w};
            float bv[8] = {c0.x, c0.y, c0.z, c0.w, c1.x, c1.y, c1.z, c1.w};
            short8 ah, al, bh, bl;
#pragma unroll
            for (int j = 0; j < 8; j++) {
                u32 pa = splitf(av[j]);
                u32 pb = splitf(bv[j]);
                ah[j] = (short)(pa >> 16);
                al[j] = (short)(pa & 0xffffu);
                bh[j] = (short)(pb >> 16);
                bl[j] = (short)(pb & 0xffffu);
            }
            acc = MFMA_BF16(ah, bh, acc);
            acc = MFMA_BF16(al, bh, acc);
            acc = MFMA_BF16(ah, bl, acc);
        }
#pragma unroll
        for (int r = 0; r < 4; r++)
            atten[(pt0 + q * 4 + r) * L_TOK + e] = acc[r];
    } else {
        // ---- langp: lang -> bf16 B-frag pack for edge ctx MFMA ----
        int bi = b - 64;
#pragma unroll
        for (int p = 0; p < 2; p++) {
            int tile = wid * 2 + p;
            short8 v;
            if (q < 2) {
#pragma unroll
                for (int j = 0; j < 8; j++)
                    v[j] = f2bf(lang[bi * L_TOK * FDIM + (q * 8 + j) * FDIM + tile * 16 + e]);
            } else {
#pragma unroll
                for (int j = 0; j < 8; j++) v[j] = 0;
            }
            *(short8*)(langp + ((bi * 8 + tile) * 64 + lane) * 8) = v;
        }
    }
}

// =====================================================================
// K4: edge kernel — ONE QUERY PER WAVE, zero LDS, zero barriers.
// Wr2/lang pre-packed bf16 B-frag (w2pe/langp).
// =====================================================================
__global__ __launch_bounds__(256) void edge_kernel(const float* __restrict__ xyz,
                                                   const float* __restrict__ mask,
                                                   const float* __restrict__ Wr1,
                                                   const float* __restrict__ br1,
                                                   const float* __restrict__ br2,
                                                   const int* __restrict__ knn,
                                                   const short* __restrict__ w2pe,
                                                   const short* __restrict__ langp,
                                                   const float* __restrict__ feats,
                                                   const float* __restrict__ atten,
                                                   float* __restrict__ out) {
    int lane = threadIdx.x & 63;
    int wid  = threadIdx.x >> 6;
    int i    = blockIdx.x * 4 + wid;          // query
    int bi   = i >> 10;
    int quad = lane >> 4;
    int e16  = lane & 15;

    int idxe = knn[i * KNN + e16];

    // ---- gather logits: this lane holds l = quad*8 + j (quads 0,1 real) ----
    float sat[8];
    if (quad < 2) {
        const float4* ap = (const float4*)(atten + idxe * L_TOK + quad * 8);
        float4 a0 = ap[0], a1 = ap[1];
        sat[0] = a0.x; sat[1] = a0.y; sat[2] = a0.z; sat[3] = a0.w;
        sat[4] = a1.x; sat[5] = a1.y; sat[6] = a1.z; sat[7] = a1.w;
    } else {
#pragma unroll
        for (int j = 0; j < 8; j++) sat[j] = 0.f;
    }

    // ---- segment softmax over e (16-lane shuffle groups) ----
    float mx[8];
#pragma unroll
    for (int j = 0; j < 8; j++) mx[j] = sat[j];
#pragma unroll
    for (int off = 1; off < 16; off <<= 1) {
#pragma unroll
        for (int j = 0; j < 8; j++) mx[j] = fmaxf(mx[j], __shfl_xor(mx[j], off, 16));
    }
    float ex[8], sm[8];
#pragma unroll
    for (int j = 0; j < 8; j++) { ex[j] = __expf(sat[j] - mx[j]); sm[j] = ex[j]; }
#pragma unroll
    for (int off = 1; off < 16; off <<= 1) {
#pragma unroll
        for (int j = 0; j < 8; j++) sm[j] += __shfl_xor(sm[j], off, 16);
    }
    float st[8];
    if (quad < 2) {
        const float4* mp = (const float4*)(mask + i * L_TOK + quad * 8);
        float4 m0 = mp[0], m1 = mp[1];
        float mv[8] = {m0.x, m0.y, m0.z, m0.w, m1.x, m1.y, m1.z, m1.w};
#pragma unroll
        for (int j = 0; j < 8; j++) st[j] = ex[j] * (mv[j] / sm[j]);
    } else {
#pragma unroll
        for (int j = 0; j < 8; j++) st[j] = 0.f;
    }
    // per-e normalization over l (sum across the two real quads)
    float s = st[0] + st[1] + st[2] + st[3] + st[4] + st[5] + st[6] + st[7];
    s += __shfl_xor(s, 16, 64);
    s += __shfl_xor(s, 32, 64);
    float inv2 = 1.f / (s + 1e-7f);
    short8 sattA;
#pragma unroll
    for (int j = 0; j < 8; j++) sattA[j] = f2bf(st[j] * inv2);

    // ---- rel_encoder hidden: hid[e=lane&15][k = s*32+quad*8+j] ----
    float xi0 = xyz[i * 3 + 0], xi1 = xyz[i * 3 + 1], xi2 = xyz[i * 3 + 2];
    float xj0 = xyz[idxe * 3 + 0], xj1 = xyz[idxe * 3 + 1], xj2 = xyz[idxe * 3 + 2];
    float d0 = xi0 - xj0, d1 = xi1 - xj1, d2v = xi2 - xj2;
    float nr = sqrtf(d0 * d0 + d1 * d1 + d2v * d2v + 1e-12f);
    float ein[10] = {xi0, xi1, xi2, xj0, xj1, xj2, d0, d1, d2v, nr};
    short8 hidA[2];
#pragma unroll
    for (int sstep = 0; sstep < 2; sstep++) {
        int k0 = sstep * 32 + quad * 8;
        float h[8];
        const float4* bp = (const float4*)(br1 + k0);
        float4 b0 = bp[0], b1v = bp[1];
        h[0] = b0.x; h[1] = b0.y; h[2] = b0.z; h[3] = b0.w;
        h[4] = b1v.x; h[5] = b1v.y; h[6] = b1v.z; h[7] = b1v.w;
#pragma unroll
        for (int m = 0; m < 10; m++) {
            const float4* wp = (const float4*)(Wr1 + m * RH + k0);
            float4 w0 = wp[0], w1 = wp[1];
            float em = ein[m];
            h[0] += em * w0.x; h[1] += em * w0.y; h[2] += em * w0.z; h[3] += em * w0.w;
            h[4] += em * w1.x; h[5] += em * w1.y; h[6] += em * w1.z; h[7] += em * w1.w;
        }
#pragma unroll
        for (int j = 0; j < 8; j++) hidA[sstep][j] = f2bf(fmaxf(h[j], 0.f));
    }

    // row (e) indices for the C-layout gathers: e = quad*4 + r
    int idxr[4];
#pragma unroll
    for (int r = 0; r < 4; r++) idxr[r] = knn[i * KNN + quad * 4 + r];

    // ---- per c-tile: ew MFMA (2 steps) + ctx MFMA (1 padded step) ----
#pragma unroll 2
    for (int tile = 0; tile < 8; tile++) {
        int cc = tile * 16 + e16;
        f32x4 accew = {0.f, 0.f, 0.f, 0.f};
#pragma unroll
        for (int sstep = 0; sstep < 2; sstep++) {
            short8 w2B = *(const short8*)(w2pe + ((sstep * 8 + tile) * 64 + lane) * 8);
            accew = MFMA_BF16(hidA[sstep], w2B, accew);
        }
        short8 lsB = *(const short8*)(langp + ((bi * 8 + tile) * 64 + lane) * 8);
        f32x4 accctx = {0.f, 0.f, 0.f, 0.f};
        accctx = MFMA_BF16(sattA, lsB, accctx);

        float br2c = br2[cc];
        float msum = 0.f;
#pragma unroll
        for (int r = 0; r < 4; r++) {
            float fj = feats[idxr[r] * FDIM + cc];
            msum += fj * accctx[r] * (accew[r] + br2c);
        }
        msum += __shfl_xor(msum, 16, 64);
        msum += __shfl_xor(msum, 32, 64);
        if (lane < 16)
            out[i * FDIM + cc] = feats[i * FDIM + cc] + msum;
    }
}

extern "C" void kernel_launch(void* const* d_in, const int* in_sizes, int n_in,
                              void* d_out, int out_size, void* d_ws, size_t ws_size,
                              hipStream_t stream) {
    const float* xyz   = (const float*)d_in[0];
    // d_in[1] = batch_index (int32) — layout-implied (i>>10), unused
    const float* features = (const float*)d_in[2];
    const float* lang_f   = (const float*)d_in[3];
    const float* mask     = (const float*)d_in[4];
    const float* W1   = (const float*)d_in[5];
    const float* b1   = (const float*)d_in[6];
    const float* ln_g = (const float*)d_in[7];
    const float* ln_b = (const float*)d_in[8];
    const float* W2   = (const float*)d_in[9];
    const float* b2   = (const float*)d_in[10];
    const float* Wl1  = (const float*)d_in[11];
    const float* bl1  = (const float*)d_in[12];
    const float* bn_g = (const float*)d_in[13];
    const float* bn_b = (const float*)d_in[14];
    const float* Wl2  = (const float*)d_in[15];
    const float* bl2  = (const float*)d_in[16];
    const float* Wr1  = (const float*)d_in[17];
    const float* br1  = (const float*)d_in[18];
    const float* Wr2  = (const float*)d_in[19];
    const float* br2  = (const float*)d_in[20];

    float* ws_feats = (float*)d_ws;                       // N*F
    float* ws_atten = ws_feats + N_PTS * FDIM;            // N*L
    float* ws_lang  = ws_atten + N_PTS * L_TOK;           // B*L*F
    float* ws_hl    = ws_lang + B_SZ * L_TOK * FDIM;      // 64*F
    int*   ws_knn   = (int*)(ws_hl + 64 * FDIM);          // N*K
    short* w1p_hi   = (short*)(ws_knn + N_PTS * KNN);     // FV*F bf16
    short* w1p_lo   = w1p_hi + FV * FDIM;
    short* w2p_hi   = w1p_lo + FV * FDIM;                 // F*F
    short* w2p_lo   = w2p_hi + FDIM * FDIM;
    short* w2pe     = w2p_lo + FDIM * FDIM;               // RH*F bf16 (f2bf)
    short* langp    = w2pe + RH * FDIM;                   // B*8*64*8 bf16

    k1_kernel<<<1102, 256, 0, stream>>>(xyz, lang_f, Wl1, bl1, W1, W2, Wr2,
                                        ws_knn, ws_hl,
                                        w1p_hi, w1p_lo, w2p_hi, w2p_lo, w2pe);
    k2_kernel<<<80, 256, 0, stream>>>(features, w1p_hi, w1p_lo, w2p_hi, w2p_lo,
                                      b1, ln_g, ln_b, b2,
                                      ws_hl, bn_g, bn_b, Wl2, bl2,
                                      ws_feats, ws_lang);
    atten_kernel<<<68, 256, 0, stream>>>(ws_feats, ws_lang, ws_atten, langp);
    edge_kernel<<<N_PTS / 4, 256, 0, stream>>>(xyz, mask, Wr1, br1, br2,
                                               ws_knn, w2pe, langp, ws_feats, ws_atten,
                                               (float*)d_out);
}